// Round 1
// baseline (118.562 us; speedup 1.0000x reference)
//
#include <hip/hip_runtime.h>

// TransformerBlockQuantum: [128, 8192, 8] fp32 in/out.
// R9 = R8 with the MFMA FFN replaced by in-thread v_dot2_f32_f16 against
// SGPR-resident packed weights. Rationale: the MFMA path spent ~53 LDS
// wave-insts/wave (zbuf/hbuf/fbuf transposes) to feed 12 MFMAs -> ~10us of
// CU LDS-pipe occupancy, on par with the HBM floor, plus serial
// ds_write->ds_read chains per group. Pure dot2 costs +256 VALU/thread but
// zero LDS, zero sync, fully independent threads -> HBM-bound (~10.6us).

#define NTOK   (128 * 8192)              // 1048576 tokens
#define NTHREADS 256
#define NBLOCKS  (NTOK / NTHREADS)       // 4096
#define LN_EPS 1e-5f
#define INV2PI 0.15915494309189535f

typedef __fp16 half2_t __attribute__((ext_vector_type(2)));

union PK  { unsigned u; half2_t h; };

__device__ __forceinline__ float fast_cos_rev(float xrev) {
    return __builtin_amdgcn_cosf(xrev);        // v_cos_f32: revolutions in
}
__device__ __forceinline__ float fast_cos(float x) {
    return __builtin_amdgcn_cosf(x * INV2PI);
}
__device__ __forceinline__ float fast_rsqrt(float x) {
    return __builtin_amdgcn_rsqf(x);
}
__device__ __forceinline__ unsigned packh2(float a, float b) {
    PK c; c.h = __builtin_amdgcn_cvt_pkrtz(a, b); return c.u;
}
__device__ __forceinline__ float dot2(half2_t a, unsigned bw, float c) {
    PK b; b.u = bw;
    return __builtin_amdgcn_fdot2(a, b.h, c, false);
}

// ---- prep kernel ----------------------------------------------------------
// ws layout (uint32 words):
//   [0,32)    WqP[k][p]   = (Wq[2p][k], Wq[2p+1][k]) * INV2PI   (dot2 pairs)
//   [32,64)   WcP[kp][j]  = (Wc[2kp][j], Wc[2kp+1][j])          (dot2 pairs)
//   [64,72)   qbias[k]    = (bq[k]+tha[k]) * INV2PI   (float bits)
//   [72,80)   cf[j]       = cos(theta_ffn[j])          (float bits)
//   [80,208)  W1P[p][n]   = (W1[2p][n], W1[2p+1][n])   p<4,  n<32
//   [208,336) W2P[p][j]   = (W2[2p][j], W2[2p+1][j])   p<16, j<8
__global__ void pack_weights(const float* __restrict__ Wq,
                             const float* __restrict__ W1,
                             const float* __restrict__ W2,
                             const float* __restrict__ Wc,
                             const float* __restrict__ bq,
                             const float* __restrict__ tha,
                             const float* __restrict__ thf,
                             unsigned* __restrict__ ws)
{
    int idx = threadIdx.x;
    if (idx < 32) {
        int k = idx >> 2, p = idx & 3;
        ws[idx] = packh2(Wq[(2 * p) * 8 + k] * INV2PI, Wq[(2 * p + 1) * 8 + k] * INV2PI);
    } else if (idx < 64) {
        int i2 = idx - 32;
        int kp = i2 >> 3, j = i2 & 7;
        ws[idx] = packh2(Wc[(2 * kp) * 8 + j], Wc[(2 * kp + 1) * 8 + j]);
    } else if (idx < 72) {
        int k = idx - 64;
        ws[idx] = __float_as_uint((bq[k] + tha[k]) * INV2PI);
    } else if (idx < 80) {
        int j = idx - 72;
        ws[idx] = __float_as_uint(__builtin_amdgcn_cosf(thf[j] * INV2PI));
    } else if (idx < 208) {
        int i = idx - 80;
        int p = i >> 5, n = i & 31;
        ws[idx] = packh2(W1[(2 * p) * 32 + n], W1[(2 * p + 1) * 32 + n]);
    } else if (idx < 336) {
        int i = idx - 208;
        int p = i >> 3, j = i & 7;
        ws[idx] = packh2(W2[(2 * p) * 8 + j], W2[(2 * p + 1) * 8 + j]);
    }
}

// ---- main kernel ----------------------------------------------------------
__global__ __launch_bounds__(NTHREADS, 8)
void qtb_kernel(const float* __restrict__ x,
                const float* __restrict__ bc,
                const float* __restrict__ g1,  const float* __restrict__ be1,
                const float* __restrict__ b1,
                const float* __restrict__ b2,
                const float* __restrict__ g2,  const float* __restrict__ be2,
                const unsigned* __restrict__ wp,
                float* __restrict__ out)
{
    const int g = blockIdx.x * NTHREADS + threadIdx.x;   // token id

    // ---- x load first: start HBM latency before everything else ----
    const float4* px = reinterpret_cast<const float4*>(x) + (size_t)g * 2;
    float4 xa = px[0];
    float4 xb = px[1];

    const float* qb = reinterpret_cast<const float*>(wp + 64);
    const float* cf = reinterpret_cast<const float*>(wp + 72);

    float xv[8];
    half2_t xp[4];
    xv[0] = xa.x; xv[1] = xa.y; xv[2] = xa.z; xv[3] = xa.w;
    xv[4] = xb.x; xv[5] = xb.y; xv[6] = xb.z; xv[7] = xb.w;
    xp[0] = __builtin_amdgcn_cvt_pkrtz(xa.x, xa.y);
    xp[1] = __builtin_amdgcn_cvt_pkrtz(xa.z, xa.w);
    xp[2] = __builtin_amdgcn_cvt_pkrtz(xb.x, xb.y);
    xp[3] = __builtin_amdgcn_cvt_pkrtz(xb.z, xb.w);

    // ---- attention: q (revolutions) via dot2, cos, cumprods, z@Wc via dot2 ----
    float ca[8];
#pragma unroll
    for (int k = 0; k < 8; ++k) {
        float q = qb[k];
#pragma unroll
        for (int p = 0; p < 4; ++p) q = dot2(xp[p], wp[k * 4 + p], q);
        ca[k] = fast_cos_rev(q);
    }
    float attn[8];
#pragma unroll
    for (int j = 0; j < 8; ++j) attn[j] = bc[j];
    {
        float z[8];
        float cp  = ca[0];
        float cp1 = 1.0f;
#pragma unroll
        for (int k = 1; k < 8; ++k) {
            cp  *= ca[k];
            cp1 *= ca[k];
            z[k] = cp;
        }
        z[0] = cp1;
        half2_t zp[4];
#pragma unroll
        for (int p = 0; p < 4; ++p)
            zp[p] = __builtin_amdgcn_cvt_pkrtz(z[2 * p], z[2 * p + 1]);
#pragma unroll
        for (int p = 0; p < 4; ++p)
#pragma unroll
            for (int j = 0; j < 8; ++j)
                attn[j] = dot2(zp[p], wp[32 + p * 8 + j], attn[j]);
    }

    // ---- LN1 + zf = cf * cos(x1); keep x1 in xv ----
    half2_t zp2[4];
    {
        float y[8];
        float s = 0.f;
#pragma unroll
        for (int j = 0; j < 8; ++j) { y[j] = xv[j] + attn[j]; s += y[j]; }
        float m = s * 0.125f;
        float v = 0.f;
#pragma unroll
        for (int j = 0; j < 8; ++j) { float d = y[j] - m; v += d * d; }
        float r = fast_rsqrt(v * 0.125f + LN_EPS);
        float zf[8];
#pragma unroll
        for (int j = 0; j < 8; ++j) {
            float x1 = (y[j] - m) * r * g1[j] + be1[j];
            xv[j] = x1;
            zf[j] = cf[j] * fast_cos(x1);
        }
#pragma unroll
        for (int p = 0; p < 4; ++p)
            zp2[p] = __builtin_amdgcn_cvt_pkrtz(zf[2 * p], zf[2 * p + 1]);
    }

    // ---- FFN fully in-thread: h = relu(zf@W1+b1) via dot2, then h@W2+b2 ----
    // GEMM1 in two chunks of 16 outputs to bound live f32 accumulators.
    half2_t hp[16];          // h packed as f16 feature pairs (2p, 2p+1)
#pragma unroll
    for (int c = 0; c < 2; ++c) {
        float acc[16];
#pragma unroll
        for (int n = 0; n < 16; ++n) acc[n] = b1[c * 16 + n];
#pragma unroll
        for (int p = 0; p < 4; ++p)
#pragma unroll
            for (int n = 0; n < 16; ++n)
                acc[n] = dot2(zp2[p], wp[80 + p * 32 + c * 16 + n], acc[n]);
#pragma unroll
        for (int n2 = 0; n2 < 8; ++n2)
            hp[c * 8 + n2] = __builtin_amdgcn_cvt_pkrtz(fmaxf(acc[2 * n2], 0.f),
                                                        fmaxf(acc[2 * n2 + 1], 0.f));
    }
    float o[8];
#pragma unroll
    for (int j = 0; j < 8; ++j) o[j] = b2[j];
#pragma unroll
    for (int p = 0; p < 16; ++p)
#pragma unroll
        for (int j = 0; j < 8; ++j)
            o[j] = dot2(hp[p], wp[208 + p * 8 + j], o[j]);

    // ---- LN2 + store ----
    {
        float y[8];
        float s = 0.f;
#pragma unroll
        for (int j = 0; j < 8; ++j) { y[j] = xv[j] + o[j]; s += y[j]; }
        float m = s * 0.125f;
        float v = 0.f;
#pragma unroll
        for (int j = 0; j < 8; ++j) { float d = y[j] - m; v += d * d; }
        float r = fast_rsqrt(v * 0.125f + LN_EPS);
        float ov[8];
#pragma unroll
        for (int j = 0; j < 8; ++j) ov[j] = (y[j] - m) * r * g2[j] + be2[j];
        float4* q = reinterpret_cast<float4*>(out) + (size_t)g * 2;
        q[0] = make_float4(ov[0], ov[1], ov[2], ov[3]);
        q[1] = make_float4(ov[4], ov[5], ov[6], ov[7]);
    }
}

extern "C" void kernel_launch(void* const* d_in, const int* in_sizes, int n_in,
                              void* d_out, int out_size, void* d_ws, size_t ws_size,
                              hipStream_t stream) {
    (void)in_sizes; (void)n_in; (void)ws_size; (void)out_size;
    unsigned* wp = (unsigned*)d_ws;
    pack_weights<<<1, 384, 0, stream>>>(
        (const float*)d_in[1],   // Wq
        (const float*)d_in[9],   // W1
        (const float*)d_in[11],  // W2
        (const float*)d_in[4],   // Wc
        (const float*)d_in[2],   // bq
        (const float*)d_in[3],   // theta_attn
        (const float*)d_in[8],   // theta_ffn
        wp);
    qtb_kernel<<<NBLOCKS, NTHREADS, 0, stream>>>(
        (const float*)d_in[0],  // x
        (const float*)d_in[5],  // bc
        (const float*)d_in[6],  // g1
        (const float*)d_in[7],  // beta1
        (const float*)d_in[10], // b1
        (const float*)d_in[12], // b2
        (const float*)d_in[13], // g2
        (const float*)d_in[14], // beta2
        wp,
        (float*)d_out);
}